// Round 3
// baseline (161.099 us; speedup 1.0000x reference)
//
#include <hip/hip_runtime.h>

// Problem constants
#define BATCH 16384
#define KEYD  64
#define DDIM  128
#define UDIM  128
#define MODES 32

typedef __attribute__((ext_vector_type(8))) short bf16x8;   // 8 bf16 in 4 VGPRs
typedef __attribute__((ext_vector_type(4))) float f32x4;

__device__ __forceinline__ unsigned short f2bf(float f) {
  unsigned u = __float_as_uint(f);
  unsigned r = (u + 0x7FFFu + ((u >> 16) & 1u)) >> 16;  // RNE bf16
  return (unsigned short)r;
}

// ---------------------------------------------------------------------------
// Fused prep (one dispatch):
//  blocks [0, 1024): zero an 8KB slice of out + sim softmax (16 rows) + x->bf16
//  blocks [1024, 1282): cast kernels+biases to bf16 in MFMA-B fragment layout
//    kb16[m][kblk][u][j] = kernels[m][kblk*8+j][u], bb16[kblk][u][j] likewise:
//    each B-fragment (8 k-consecutive bf16 of one column) is a contiguous 16B
//    chunk -> the GEMM loads fragments STRAIGHT from global, no LDS staging.
// ---------------------------------------------------------------------------
__global__ __launch_bounds__(256) void prep_all(
    const float* __restrict__ key, const float* __restrict__ x,
    const float* __restrict__ sens, const float* __restrict__ keys_map,
    const float* __restrict__ kernels, const float* __restrict__ biases,
    float* __restrict__ sim, unsigned short* __restrict__ x16,
    unsigned short* __restrict__ kb16, unsigned short* __restrict__ bb16,
    float* __restrict__ out) {
  const int t = threadIdx.x;
  const int bid = blockIdx.x;

  __shared__ float kmT[KEYD * MODES];  // [k][m]: lane-m reads bank-consecutive
  __shared__ float kr[16][KEYD];

  if (bid < BATCH / 16) {
    // zero this block's 8KB slice of out (gemm atomically accumulates)
    const float4 z = make_float4(0.f, 0.f, 0.f, 0.f);
    float4* op = (float4*)out + (long)bid * 512;
    op[t] = z; op[t + 256] = z;

    for (int i = t; i < MODES * KEYD; i += 256) {
      int m = i >> 6, k = i & 63;
      kmT[k * MODES + m] = keys_map[i];
    }
    *(float4*)(&kr[0][0] + t * 4) =
        *(const float4*)(key + (long)bid * 16 * KEYD + t * 4);
    __syncthreads();

    const int lane = t & 63, wave = t >> 6;
    const int half = lane >> 5, m = lane & 31;
    const float sv = sens[m];

    #pragma unroll
    for (int pass = 0; pass < 2; ++pass) {
      const int rl = pass * 8 + wave * 2 + half;
      const long row = (long)bid * 16 + rl;

      float d2 = 0.f;
      #pragma unroll
      for (int k = 0; k < KEYD; ++k) {
        float diff = kr[rl][k] - kmT[k * MODES + m];
        d2 += diff * diff;
      }
      float logit = sv / (sqrtf(d2) + 1.0f);
      float mx = logit;
      #pragma unroll
      for (int off = 16; off > 0; off >>= 1) mx = fmaxf(mx, __shfl_xor(mx, off, 64));
      float e = __expf(logit - mx);
      float s = e;
      #pragma unroll
      for (int off = 16; off > 0; off >>= 1) s += __shfl_xor(s, off, 64);
      sim[row * MODES + m] = e / s;

      const float4 xv = *(const float4*)(x + row * DDIM + m * 4);
      ushort4 o;
      o.x = f2bf(xv.x); o.y = f2bf(xv.y); o.z = f2bf(xv.z); o.w = f2bf(xv.w);
      *(ushort4*)(x16 + row * DDIM + m * 4) = o;
    }
  } else {
    int tt = (bid - BATCH / 16) * 256 + t;
    if (tt < MODES * 16 * UDIM) {  // 65536 chunks of 8
      int u = tt & 127, kb = (tt >> 7) & 15, m = tt >> 11;
      const float* src = kernels + (long)((m * 16 + kb) * 8) * UDIM + u;
      ushort4 lo, hi;
      lo.x = f2bf(src[0 * UDIM]); lo.y = f2bf(src[1 * UDIM]);
      lo.z = f2bf(src[2 * UDIM]); lo.w = f2bf(src[3 * UDIM]);
      hi.x = f2bf(src[4 * UDIM]); hi.y = f2bf(src[5 * UDIM]);
      hi.z = f2bf(src[6 * UDIM]); hi.w = f2bf(src[7 * UDIM]);
      *(ushort4*)(kb16 + (long)tt * 8) = lo;
      *(ushort4*)(kb16 + (long)tt * 8 + 4) = hi;
    } else {  // 512 bias chunks
      int tb = tt - MODES * 16 * UDIM;
      int u = tb & 127, kb = tb >> 7;
      const float* src = biases + kb * 8 * UDIM + u;
      ushort4 lo, hi;
      lo.x = f2bf(src[0 * UDIM]); lo.y = f2bf(src[1 * UDIM]);
      lo.z = f2bf(src[2 * UDIM]); lo.w = f2bf(src[3 * UDIM]);
      hi.x = f2bf(src[4 * UDIM]); hi.y = f2bf(src[5 * UDIM]);
      hi.z = f2bf(src[6 * UDIM]); hi.w = f2bf(src[7 * UDIM]);
      *(ushort4*)(bb16 + (long)tb * 8) = lo;
      *(ushort4*)(bb16 + (long)tb * 8 + 4) = hi;
    }
  }
}

// ---------------------------------------------------------------------------
// GEMM, barrier-free K-loop.  out[b,u] = (1/32)(sum_m sim[b,m]*(x@K_m) + sim@b)
// Block = 4 waves stacked in rows: block tile 128 rows x 64 cols.
// Wave tile 32x64 (acc 32 AGPR, aF 32 VGPR -> 3 waves/SIMD).
// Grid (128 row-tiles, 2 col-halves x 4 mode-splits) = 1024 blocks.
// B-fragments are loaded directly from L2-hot kb16 (fragment-contiguous
// layout), so the 8-mode loop has NO __syncthreads and the compiler
// software-pipelines loads vs MFMAs with fine-grained vmcnt (AITER-style).
// fp32 atomicAdd epilogue across the 4 mode-splits (out pre-zeroed by prep).
// ---------------------------------------------------------------------------
__global__ __launch_bounds__(256, 3) void gemm_poly(
    const unsigned short* __restrict__ x16, const unsigned short* __restrict__ kb16,
    const unsigned short* __restrict__ bb16, const float* __restrict__ sim,
    float* __restrict__ out) {
  __shared__ alignas(16) float simT[8][128];  // [mode_local][row]

  const int t = threadIdx.x;
  const int lane = t & 63, w = t >> 6;
  const int q = lane >> 4, l16 = lane & 15;
  const int wrow = w * 32;                 // wave's rows in block tile
  const long bm = (long)blockIdx.x * 128;
  const int split = blockIdx.y & 3;        // modes [split*8, split*8+8)
  const int c0 = (blockIdx.y >> 2) * 64;   // column half

  // stage sim (8 modes x 128 rows) transposed into LDS; one barrier total
  {
    int rrow = t >> 1, mg = (t & 1) * 4;
    const float4 v = *(const float4*)(sim + (bm + rrow) * MODES + split * 8 + mg);
    simT[mg + 0][rrow] = v.x; simT[mg + 1][rrow] = v.y;
    simT[mg + 2][rrow] = v.z; simT[mg + 3][rrow] = v.w;
  }
  __syncthreads();

  // A fragments (x, bf16): A[row = wrow+rt*16+l16][k = ks*32+q*8+j]
  bf16x8 aF[2][4];
  #pragma unroll
  for (int rt = 0; rt < 2; ++rt)
    #pragma unroll
    for (int ks = 0; ks < 4; ++ks)
      aF[rt][ks] = *(const bf16x8*)(x16 + (bm + wrow + rt * 16 + l16) * DDIM + ks * 32 + q * 8);

  f32x4 acc[2][4] = {};  // [rt][ct]
  const unsigned short* kbase = kb16 + (long)(split * 8) * (16 * UDIM * 8);

  #pragma unroll
  for (int mi = 0; mi < 8; ++mi) {
    const unsigned short* mb = kbase + (long)mi * (16 * UDIM * 8);
    // B fragments straight from global (L2-hot), contiguous 16B each:
    // B[k = (ks*4+q)*8+j][u = c0+ct*16+l16]
    bf16x8 bF[4][4];
    #pragma unroll
    for (int ks = 0; ks < 4; ++ks)
      #pragma unroll
      for (int ct = 0; ct < 4; ++ct)
        bF[ks][ct] = *(const bf16x8*)(mb + ((ks * 4 + q) * UDIM + c0 + ct * 16 + l16) * 8);

    #pragma unroll
    for (int rt = 0; rt < 2; ++rt) {
      f32x4 tmp[4] = {};
      #pragma unroll
      for (int ks = 0; ks < 4; ++ks)
        #pragma unroll
        for (int ct = 0; ct < 4; ++ct)
          tmp[ct] = __builtin_amdgcn_mfma_f32_16x16x32_bf16(aF[rt][ks], bF[ks][ct], tmp[ct], 0, 0, 0);
      const f32x4 s = *(const f32x4*)&simT[mi][wrow + rt * 16 + q * 4];
      #pragma unroll
      for (int ct = 0; ct < 4; ++ct)
        acc[rt][ct] += s * tmp[ct];
    }
  }

  // bias term: one K=32 MFMA round (A = sim bf16, B = biases). split 0 only.
  if (split == 0) {
    bf16x8 sF[2];
    #pragma unroll
    for (int rt = 0; rt < 2; ++rt) {
      const float* sp = sim + (bm + wrow + rt * 16 + l16) * MODES + q * 8;
      bf16x8 f;
      #pragma unroll
      for (int j = 0; j < 8; ++j) f[j] = (short)f2bf(sp[j]);
      sF[rt] = f;
    }
    #pragma unroll
    for (int ct = 0; ct < 4; ++ct) {
      bf16x8 bb = *(const bf16x8*)(bb16 + (long)(q * UDIM + c0 + ct * 16 + l16) * 8);
      #pragma unroll
      for (int rt = 0; rt < 2; ++rt)
        acc[rt][ct] = __builtin_amdgcn_mfma_f32_16x16x32_bf16(sF[rt], bb, acc[rt][ct], 0, 0, 0);
    }
  }

  // epilogue: scale 1/MODES, atomic-accumulate across mode-splits
  #pragma unroll
  for (int rt = 0; rt < 2; ++rt)
    #pragma unroll
    for (int ct = 0; ct < 4; ++ct) {
      long row = bm + wrow + rt * 16 + q * 4;
      int col = c0 + ct * 16 + l16;
      #pragma unroll
      for (int r = 0; r < 4; ++r)
        atomicAdd(out + (row + r) * UDIM + col, acc[rt][ct][r] * (1.0f / MODES));
    }
}

extern "C" void kernel_launch(void* const* d_in, const int* in_sizes, int n_in,
                              void* d_out, int out_size, void* d_ws, size_t ws_size,
                              hipStream_t stream) {
  const float* key      = (const float*)d_in[0];
  const float* x        = (const float*)d_in[1];
  const float* sens     = (const float*)d_in[2];
  const float* keys_map = (const float*)d_in[3];
  const float* kernels  = (const float*)d_in[4];
  const float* biases   = (const float*)d_in[5];
  float* out = (float*)d_out;

  char* ws = (char*)d_ws;
  float*          sim  = (float*)ws;                          // 2 MB
  unsigned short* x16  = (unsigned short*)(ws + (2u << 20));  // 4 MB
  unsigned short* kb16 = (unsigned short*)(ws + (6u << 20));  // 1 MB
  unsigned short* bb16 = (unsigned short*)(ws + (7u << 20));  // 8 KB

  // blocks [0,1024): out-zero + sim + x16; [1024,1282): kernels/biases cast
  prep_all<<<BATCH / 16 + 258, 256, 0, stream>>>(
      key, x, sens, keys_map, kernels, biases, sim, x16, kb16, bb16, out);
  gemm_poly<<<dim3(BATCH / 128, 8), 256, 0, stream>>>(x16, kb16, bb16, sim, out);
}

// Round 4
// 107.904 us; speedup vs baseline: 1.4930x; 1.4930x over previous
//
#include <hip/hip_runtime.h>

// Problem constants
#define BATCH 16384
#define KEYD  64
#define DDIM  128
#define UDIM  128
#define MODES 32

typedef __attribute__((ext_vector_type(8))) short bf16x8;   // 8 bf16 in 4 VGPRs
typedef __attribute__((ext_vector_type(4))) float f32x4;

__device__ __forceinline__ unsigned short f2bf(float f) {
  unsigned u = __float_as_uint(f);
  unsigned r = (u + 0x7FFFu + ((u >> 16) & 1u)) >> 16;  // RNE bf16
  return (unsigned short)r;
}

__device__ __forceinline__ void gld_lds16(const void* g, void* l) {
  __builtin_amdgcn_global_load_lds(
      (const __attribute__((address_space(1))) unsigned int*)g,
      (__attribute__((address_space(3))) unsigned int*)l, 16, 0, 0);
}

// ---------------------------------------------------------------------------
// Fused prep (one dispatch):
//  blocks [0,512): sim softmax (32 rows/block) + x->bf16.
//    Each lane owns HALF of one mode's key row in 32 registers
//    (lane = h*32+m); kr row read via 2-way-broadcast ds_read_b64 (free);
//    halves combined with one shfl_xor(32). 16 LDS ops/row vs 128 before.
//  blocks [512,770): cast kernels+biases to bf16 in MFMA-B fragment layout
//    kb16[m][kblk][u][j] = kernels[m][kblk*8+j][u] -> every B-fragment is a
//    contiguous 16B chunk (ds_read_b128 / global_load_lds width-16 friendly).
// ---------------------------------------------------------------------------
__global__ __launch_bounds__(256) void prep_all(
    const float* __restrict__ key, const float* __restrict__ x,
    const float* __restrict__ sens, const float* __restrict__ keys_map,
    const float* __restrict__ kernels, const float* __restrict__ biases,
    float* __restrict__ sim, unsigned short* __restrict__ x16,
    unsigned short* __restrict__ kb16, unsigned short* __restrict__ bb16) {
  const int t = threadIdx.x;
  const int bid = blockIdx.x;

  if (bid < BATCH / 32) {
    __shared__ float kr[32][KEYD];  // 32 key rows, 8KB
    // stage rows: 2048 floats = 256 threads x 2 float4, coalesced
    *(float4*)(&kr[0][0] + t * 4) =
        *(const float4*)(key + (long)bid * 32 * KEYD + t * 4);
    *(float4*)(&kr[0][0] + 1024 + t * 4) =
        *(const float4*)(key + (long)bid * 32 * KEYD + 1024 + t * 4);

    const int lane = t & 63, wave = t >> 6;
    const int m = lane & 31, h = lane >> 5;
    float kreg[32];  // this lane's half of mode m's key row
    {
      const float* kmp = keys_map + m * KEYD + h * 32;
      #pragma unroll
      for (int j = 0; j < 32; j += 4) {
        const float4 v = *(const float4*)(kmp + j);
        kreg[j] = v.x; kreg[j + 1] = v.y; kreg[j + 2] = v.z; kreg[j + 3] = v.w;
      }
    }
    const float sv = sens[m];
    __syncthreads();

    #pragma unroll
    for (int rr = 0; rr < 8; ++rr) {
      const int rl = wave * 8 + rr;
      const long row = (long)bid * 32 + rl;

      float d2h = 0.f;
      #pragma unroll
      for (int j = 0; j < 32; j += 2) {
        const float2 kv = *(const float2*)(&kr[rl][h * 32 + j]);
        float a = kv.x - kreg[j], b = kv.y - kreg[j + 1];
        d2h += a * a + b * b;
      }
      float d2 = d2h + __shfl_xor(d2h, 32, 64);  // both halves get full d2
      float logit = sv / (sqrtf(d2) + 1.0f);
      float mx = logit;
      #pragma unroll
      for (int off = 16; off > 0; off >>= 1) mx = fmaxf(mx, __shfl_xor(mx, off, 64));
      float e = __expf(logit - mx);
      float s = e;
      #pragma unroll
      for (int off = 16; off > 0; off >>= 1) s += __shfl_xor(s, off, 64);
      if (h == 0) sim[row * MODES + m] = e / s;

      // cast this row of x (128 floats): 64 lanes x float2
      const float2 xv = *(const float2*)(x + row * DDIM + lane * 2);
      ushort2 o; o.x = f2bf(xv.x); o.y = f2bf(xv.y);
      *(ushort2*)(x16 + row * DDIM + lane * 2) = o;
    }
  } else {
    int tt = (bid - BATCH / 32) * 256 + t;
    if (tt < MODES * 16 * UDIM) {  // 65536 chunks of 8
      int u = tt & 127, kb = (tt >> 7) & 15, m = tt >> 11;
      const float* src = kernels + (long)((m * 16 + kb) * 8) * UDIM + u;
      ushort4 lo, hi;
      lo.x = f2bf(src[0 * UDIM]); lo.y = f2bf(src[1 * UDIM]);
      lo.z = f2bf(src[2 * UDIM]); lo.w = f2bf(src[3 * UDIM]);
      hi.x = f2bf(src[4 * UDIM]); hi.y = f2bf(src[5 * UDIM]);
      hi.z = f2bf(src[6 * UDIM]); hi.w = f2bf(src[7 * UDIM]);
      *(ushort4*)(kb16 + (long)tt * 8) = lo;
      *(ushort4*)(kb16 + (long)tt * 8 + 4) = hi;
    } else {  // 512 bias chunks
      int tb = tt - MODES * 16 * UDIM;
      int u = tb & 127, kb = tb >> 7;
      const float* src = biases + kb * 8 * UDIM + u;
      ushort4 lo, hi;
      lo.x = f2bf(src[0 * UDIM]); lo.y = f2bf(src[1 * UDIM]);
      lo.z = f2bf(src[2 * UDIM]); lo.w = f2bf(src[3 * UDIM]);
      hi.x = f2bf(src[4 * UDIM]); hi.y = f2bf(src[5 * UDIM]);
      hi.z = f2bf(src[6 * UDIM]); hi.w = f2bf(src[7 * UDIM]);
      *(ushort4*)(bb16 + (long)tb * 8) = lo;
      *(ushort4*)(bb16 + (long)tb * 8 + 4) = hi;
    }
  }
}

// ---------------------------------------------------------------------------
// GEMM (R2 structure: dbuf LDS staging, 1 barrier/mode), but the epilogue is
// PLAIN STORES into a per-split partial buffer — no atomics, no RMW, no
// pre-zeroed out. Block tile 128x128, 4 waves of 64x64, grid (128, 4 splits).
// ---------------------------------------------------------------------------
__global__ __launch_bounds__(256, 2) void gemm_poly(
    const unsigned short* __restrict__ x16, const unsigned short* __restrict__ kb16,
    const unsigned short* __restrict__ bb16, const float* __restrict__ sim,
    float* __restrict__ partial) {
  __shared__ alignas(16) unsigned short bsh[2][16 * UDIM * 8];  // 2 x 32KB
  __shared__ alignas(16) float simT[8][128];                    // [mode_local][row]

  const int t = threadIdx.x;
  const int lane = t & 63, w = t >> 6;
  const int q = lane >> 4, l16 = lane & 15;
  const int wrow = (w >> 1) * 64, wcol = (w & 1) * 64;
  const long bm = (long)blockIdx.x * 128;
  const int split = blockIdx.y;  // modes [split*8, split*8+8)

  {  // stage sim (own 8 modes, 128 rows) transposed into LDS
    int rrow = t >> 1, mg = (t & 1) * 4;
    const float4 v = *(const float4*)(sim + (bm + rrow) * MODES + split * 8 + mg);
    simT[mg + 0][rrow] = v.x; simT[mg + 1][rrow] = v.y;
    simT[mg + 2][rrow] = v.z; simT[mg + 3][rrow] = v.w;
  }

  // A fragments (x, bf16): A[row = wrow+rt*16+l16][k = ks*32+q*8+j]
  bf16x8 aF[4][4];
  #pragma unroll
  for (int rt = 0; rt < 4; ++rt)
    #pragma unroll
    for (int ks = 0; ks < 4; ++ks)
      aF[rt][ks] = *(const bf16x8*)(x16 + (bm + wrow + rt * 16 + l16) * DDIM + ks * 32 + q * 8);

  const unsigned short* kbase = kb16 + (long)(split * 8) * (16 * UDIM * 8);
  #pragma unroll
  for (int i = 0; i < 8; ++i) {  // stage mode 0 into buffer 0
    int off = (t + i * 256) * 8;
    gld_lds16(kbase + off, &bsh[0][off]);
  }

  f32x4 acc[4][4] = {};  // [rt][ct]

  for (int mi = 0; mi < 8; ++mi) {
    __syncthreads();  // drains vmcnt: bsh[mi&1] staged; prev-iter reads done
    if (mi < 7) {     // prefetch next mode into the other buffer
      const unsigned short* src = kbase + (long)(mi + 1) * (16 * UDIM * 8);
      unsigned short* dst = bsh[(mi + 1) & 1];
      #pragma unroll
      for (int i = 0; i < 8; ++i) {
        int off = (t + i * 256) * 8;
        gld_lds16(src + off, dst + off);
      }
    }

    const unsigned short* bs = bsh[mi & 1];
    bf16x8 bF[4][4];  // [ks][ct], contiguous 16B each, conflict-free b128
    #pragma unroll
    for (int ks = 0; ks < 4; ++ks)
      #pragma unroll
      for (int ct = 0; ct < 4; ++ct)
        bF[ks][ct] = *(const bf16x8*)&bs[(((ks * 4 + q) * UDIM) + wcol + ct * 16 + l16) * 8];

    #pragma unroll
    for (int rt = 0; rt < 4; ++rt) {
      f32x4 tmp[4] = {};
      #pragma unroll
      for (int ks = 0; ks < 4; ++ks)
        #pragma unroll
        for (int ct = 0; ct < 4; ++ct)
          tmp[ct] = __builtin_amdgcn_mfma_f32_16x16x32_bf16(aF[rt][ks], bF[ks][ct], tmp[ct], 0, 0, 0);
      const f32x4 s = *(const f32x4*)&simT[mi][wrow + rt * 16 + q * 4];
      #pragma unroll
      for (int ct = 0; ct < 4; ++ct)
        acc[rt][ct] += s * tmp[ct];
    }
  }

  // bias term: one K=32 MFMA round (A = sim bf16, B = biases). split 0 only.
  if (split == 0) {
    bf16x8 sF[4];
    #pragma unroll
    for (int rt = 0; rt < 4; ++rt) {
      const float* sp = sim + (bm + wrow + rt * 16 + l16) * MODES + q * 8;
      bf16x8 f;
      #pragma unroll
      for (int j = 0; j < 8; ++j) f[j] = (short)f2bf(sp[j]);
      sF[rt] = f;
    }
    #pragma unroll
    for (int ct = 0; ct < 4; ++ct) {
      bf16x8 bb = *(const bf16x8*)(bb16 + (long)(q * UDIM + wcol + ct * 16 + l16) * 8);
      #pragma unroll
      for (int rt = 0; rt < 4; ++rt)
        acc[rt][ct] = __builtin_amdgcn_mfma_f32_16x16x32_bf16(sF[rt], bb, acc[rt][ct], 0, 0, 0);
    }
  }

  // epilogue: plain stores to this split's private partial buffer
  float* part = partial + (long)split * ((long)BATCH * UDIM);
  #pragma unroll
  for (int rt = 0; rt < 4; ++rt)
    #pragma unroll
    for (int ct = 0; ct < 4; ++ct) {
      long row = bm + wrow + rt * 16 + q * 4;
      int col = wcol + ct * 16 + l16;
      #pragma unroll
      for (int r = 0; r < 4; ++r)
        part[(row + r) * UDIM + col] = acc[rt][ct][r];
    }
}

// ---------------------------------------------------------------------------
// Streaming reduce: out = (p0+p1+p2+p3) / MODES.  2M floats as float4.
// ---------------------------------------------------------------------------
__global__ __launch_bounds__(256) void reduce_parts(
    const float* __restrict__ partial, float* __restrict__ out) {
  const long i = ((long)blockIdx.x * 256 + threadIdx.x) * 4;
  const long S = (long)BATCH * UDIM;
  const f32x4 p0 = *(const f32x4*)(partial + i);
  const f32x4 p1 = *(const f32x4*)(partial + S + i);
  const f32x4 p2 = *(const f32x4*)(partial + 2 * S + i);
  const f32x4 p3 = *(const f32x4*)(partial + 3 * S + i);
  *(f32x4*)(out + i) = (p0 + p1 + p2 + p3) * (1.0f / MODES);
}

extern "C" void kernel_launch(void* const* d_in, const int* in_sizes, int n_in,
                              void* d_out, int out_size, void* d_ws, size_t ws_size,
                              hipStream_t stream) {
  const float* key      = (const float*)d_in[0];
  const float* x        = (const float*)d_in[1];
  const float* sens     = (const float*)d_in[2];
  const float* keys_map = (const float*)d_in[3];
  const float* kernels  = (const float*)d_in[4];
  const float* biases   = (const float*)d_in[5];
  float* out = (float*)d_out;

  char* ws = (char*)d_ws;
  float*          sim  = (float*)ws;                          // 2 MB
  unsigned short* x16  = (unsigned short*)(ws + (2u << 20));  // 4 MB
  unsigned short* kb16 = (unsigned short*)(ws + (6u << 20));  // 1 MB
  unsigned short* bb16 = (unsigned short*)(ws + (7u << 20));  // 8 KB
  float*          part = (float*)(ws + (8u << 20));           // 4 x 8.4 MB

  prep_all<<<BATCH / 32 + 258, 256, 0, stream>>>(
      key, x, sens, keys_map, kernels, biases, sim, x16, kb16, bb16);
  gemm_poly<<<dim3(BATCH / 128, 4), 256, 0, stream>>>(x16, kb16, bb16, sim, part);
  reduce_parts<<<(BATCH * UDIM) / (256 * 4), 256, 0, stream>>>(part, out);
}